// Round 15
// baseline (131.973 us; speedup 1.0000x reference)
//
#include <hip/hip_runtime.h>

#define B_ 8
#define T_ 256
#define U_ 64
#define U1_ 65
#define V_ 512
#define NDIAGP_ 336   // padded diagonal count (GLDS over-read stays in-bounds)
#define NT_ 4         // t-rows per k_logprobs block
#define CH_ 64        // diagonals per k_alpha chunk

#define LOG2E_ 1.4426950408889634f
#define LN2_   0.6931471805599453f

#if __has_builtin(__builtin_amdgcn_exp2f)
#define EXP2(x) __builtin_amdgcn_exp2f(x)
#else
#define EXP2(x) exp2f(x)
#endif

// ---------------------------------------------------------------------------
// Kernel 0: edec = exp(dec) (float4); thread 0 also zeroes the output scalar.
// ---------------------------------------------------------------------------
__global__ __launch_bounds__(256) void k_exp(const float* __restrict__ x,
                                             float* __restrict__ y, int n4,
                                             float* __restrict__ out)
{
    int i = blockIdx.x * blockDim.x + threadIdx.x;
    if (i == 0) out[0] = 0.0f;
    if (i < n4) {
        float4 v = ((const float4*)x)[i];
        float4 r;
        r.x = __expf(v.x); r.y = __expf(v.y);
        r.z = __expf(v.z); r.w = __expf(v.w);
        ((float4*)y)[i] = r;
    }
}

// ---------------------------------------------------------------------------
// Kernel 1: block = (b, group of 4 t's). lse2[u] = log2( exp(enc_row) . edec_row[u] ).
// Diagonal-major log2-domain outputs:
//   BLD[b][t+u][u]  (stride 65) = (enc[0]+dec[u][0])*log2e     - lse2
//   EMD[b][t+u][u]  (stride 64) = (enc[tgt]+dec[u][tgt])*log2e - lse2
// ---------------------------------------------------------------------------
__global__ __launch_bounds__(256) void k_logprobs(
    const float* __restrict__ enc, const float* __restrict__ dec,
    const float* __restrict__ edec, const int* __restrict__ targets,
    float* __restrict__ BLD, float* __restrict__ EMD)
{
    const int blk  = blockIdx.x;           // 0 .. B_*T_/NT_ - 1
    const int b    = blk % B_;
    const int tg   = blk / B_;
    const int t0   = tg * NT_;
    const int wave = threadIdx.x >> 6;
    const int lane = threadIdx.x & 63;

    float4 xe0[NT_], xe1[NT_];
    #pragma unroll
    for (int j = 0; j < NT_; ++j) {
        const float* erow = enc + (size_t)(b * T_ + t0 + j) * V_;
        float4 e0 = *(const float4*)(erow + lane * 4);
        float4 e1 = *(const float4*)(erow + 256 + lane * 4);
        xe0[j].x = __expf(e0.x); xe0[j].y = __expf(e0.y);
        xe0[j].z = __expf(e0.z); xe0[j].w = __expf(e0.w);
        xe1[j].x = __expf(e1.x); xe1[j].y = __expf(e1.y);
        xe1[j].z = __expf(e1.z); xe1[j].w = __expf(e1.w);
    }

    for (int u = wave; u <= U_; u += 4) {
        const float* xdrow = edec + (size_t)(b * U1_ + u) * V_;
        float4 d0 = *(const float4*)(xdrow + lane * 4);
        float4 d1 = *(const float4*)(xdrow + 256 + lane * 4);

        float s[NT_];
        #pragma unroll
        for (int j = 0; j < NT_; ++j) {
            float sA = xe0[j].x * d0.x;
            float sB = xe1[j].x * d1.x;
            sA = fmaf(xe0[j].y, d0.y, sA);  sB = fmaf(xe1[j].y, d1.y, sB);
            sA = fmaf(xe0[j].z, d0.z, sA);  sB = fmaf(xe1[j].z, d1.z, sB);
            sA = fmaf(xe0[j].w, d0.w, sA);  sB = fmaf(xe1[j].w, d1.w, sB);
            s[j] = sA + sB;
        }

        #pragma unroll
        for (int off = 32; off > 0; off >>= 1) {
            #pragma unroll
            for (int j = 0; j < NT_; ++j)
                s[j] += __shfl_xor(s[j], off, 64);
        }

        if (lane == 0) {
            const float* dr = dec + (size_t)(b * U1_ + u) * V_;
            const float d_blank = dr[0];
            int   tgt = 0;
            float d_tgt = 0.0f;
            if (u < U_) { tgt = targets[b * U_ + u]; d_tgt = dr[tgt]; }
            #pragma unroll
            for (int j = 0; j < NT_; ++j) {
                const int t  = t0 + j;
                const int dg = t + u;
                const float lse2 = log2f(s[j]);
                const float* er = enc + (size_t)(b * T_ + t) * V_;
                BLD[((size_t)b * NDIAGP_ + dg) * U1_ + u] =
                    (er[0] + d_blank) * LOG2E_ - lse2;
                if (u < U_)
                    EMD[((size_t)b * NDIAGP_ + dg) * U_ + u] =
                        (er[tgt] + d_tgt) * LOG2E_ - lse2;
            }
        }
    }
}

// ---------------------------------------------------------------------------
// Kernel 2: identical math to R14 (passed, absmax 0). `sink` is where the
// final atomicAdd lands — d_ws scratch for measurement replicas, d_out for
// the real run. MEASUREMENT ROUND: launched 5x to expose its true duration
// in the timed graph: k_alpha = (dur - 55.4us)/4 - launch_overhead.
// ---------------------------------------------------------------------------
__device__ __forceinline__ float wshr1(float x) {
    return __int_as_float(__builtin_amdgcn_update_dpp(
        0, __float_as_int(x), 0x138, 0xf, 0xf, true));
}
template <int CTRL>
__device__ __forceinline__ float dppmax(float x) {
    return fmaxf(x, __int_as_float(__builtin_amdgcn_update_dpp(
        0, __float_as_int(x), CTRL, 0xf, 0xf, false)));
}
__device__ __forceinline__ float wave_max64(float x) {
    x = dppmax<0x111>(x);  // row_shr:1
    x = dppmax<0x112>(x);  // row_shr:2
    x = dppmax<0x114>(x);  // row_shr:4
    x = dppmax<0x118>(x);  // row_shr:8
    x = dppmax<0x142>(x);  // row_bcast:15
    x = dppmax<0x143>(x);  // row_bcast:31
    return __int_as_float(__builtin_amdgcn_readlane(__float_as_int(x), 63));
}

#define GLDS(c_) do {                                                           \
    if (wave > 0) {                                                             \
        const float* gbl = BLb + (size_t)(c_) * CH_ * U1_;                      \
        const float* gem = EMb + (size_t)(c_) * CH_ * U_;                       \
        float* lbl_ = sRBL[(c_) & 1];                                           \
        float* lem_ = sREM[(c_) & 1];                                           \
        for (int i = wave - 1; i < 17; i += 3)                                  \
            __builtin_amdgcn_global_load_lds(                                   \
                (const __attribute__((address_space(1))) void*)(gbl + i * 256 + lane * 4), \
                (__attribute__((address_space(3))) void*)(lbl_ + i * 256), 16, 0, 0);      \
        for (int i = wave - 1; i < 16; i += 3)                                  \
            __builtin_amdgcn_global_load_lds(                                   \
                (const __attribute__((address_space(1))) void*)(gem + i * 256 + lane * 4), \
                (__attribute__((address_space(3))) void*)(lem_ + i * 256), 16, 0, 0);      \
    }                                                                           \
} while (0)

#define CONV(c_) do {                                                           \
    if (wave > 0) {                                                             \
        const float* rbl = sRBL[(c_) & 1];                                      \
        const float* rem = sREM[(c_) & 1];                                      \
        float2* pv_ = sPV[(c_) & 1];                                            \
        float*  pc_ = sPC[(c_) & 1];                                            \
        _Pragma("unroll 4")                                                     \
        for (int i = wave - 1; i < CH_; i += 3) {                               \
            const float bl = rbl[i * U1_ + lane + 1];                           \
            const float em = rem[i * U_ + lane];                                \
            const float pc = ((c_) == 4) ? rbl[i * U1_ + i + 1]                 \
                                         : rbl[i * U1_];                        \
            float vb = fminf(bl - pc, 126.0f);                                  \
            float ve = fminf(em - pc, 126.0f);                                  \
            if ((c_) == 0 && lane == i) vb = -200.0f;                           \
            if ((c_) == 4 && lane <= i) { vb = -200.0f; ve = -200.0f; }         \
            pv_[i * 64 + lane] = make_float2(EXP2(vb), EXP2(ve));               \
            if (lane == 0) pc_[i] = pc;                                         \
        }                                                                       \
    }                                                                           \
} while (0)

#define LOADG(PV, PC, g_) do {                                                  \
    _Pragma("unroll")                                                           \
    for (int j = 0; j < 8; ++j) {                                               \
        PV[j] = pvb[(8 * (g_) + j) * 64 + lane];                                \
        PC[j] = pcb[8 * (g_) + j];                                              \
    }                                                                           \
} while (0)

#define COMPG(PV, PC, g_) do {                                                  \
    _Pragma("unroll")                                                           \
    for (int j = 0; j < 8; ++j) {                                               \
        const int d = d0 + 8 * (g_) + j + 1;                                    \
        float sr = wshr1(r);                                                    \
        sr = lane0 ? r0 : sr;                                                   \
        r = fmaf(sr, PV[j].y, r * PV[j].x);                                     \
        const bool cap = (d == cap_d);                                          \
        savedV = cap ? (tlpos ? r : r0) : savedV;                               \
        savedC = cap ? (tlpos ? Rc + PC[j] : Rc) : savedC;                      \
        Rc += PC[j];                                                            \
    }                                                                           \
    {                                                                           \
        float m = wave_max64(r);                                                \
        int mb = __float_as_int(m);                                             \
        int e = (mb >> 23) - 127;                                               \
        e = (mb >= 0x00800000) ? e : 0;                                         \
        float sc = __int_as_float((127 - e) << 23);                             \
        r *= sc;  r0 *= sc;  Rc += (float)e;                                    \
    }                                                                           \
} while (0)

#define CHUNK_BODY(c_) do {                                                     \
    const float2* pvb = sPV[(c_) & 1];                                          \
    const float*  pcb = sPC[(c_) & 1];                                          \
    const int d0 = CH_ * (c_);                                                  \
    float2 pvA[8], pvB[8];                                                      \
    float  pcA[8], pcB[8];                                                      \
    LOADG(pvA, pcA, 0);                                                         \
    for (int g = 0; g < 8; g += 2) {                                            \
        LOADG(pvB, pcB, g + 1);                                                 \
        COMPG(pvA, pcA, g);                                                     \
        if (g + 2 < 8) LOADG(pvA, pcA, g + 2);                                  \
        COMPG(pvB, pcB, g + 1);                                                 \
    }                                                                           \
} while (0)

__global__ __launch_bounds__(256) void k_alpha(
    const float* __restrict__ BLD, const float* __restrict__ EMD,
    const int* __restrict__ il_, const int* __restrict__ tl_,
    float* __restrict__ sink)
{
    __shared__ __align__(16) float  sRBL[2][17 * 256];
    __shared__ __align__(16) float  sREM[2][16 * 256];
    __shared__ __align__(16) float2 sPV[2][CH_ * 64];
    __shared__ float sPC[2][CH_];

    const int b    = blockIdx.x;
    const int wave = threadIdx.x >> 6;
    const int lane = threadIdx.x & 63;
    const int il   = il_[b];
    const int tl   = tl_[b];
    const int dstar = il - 1 + tl;
    const float* BLb = BLD + (size_t)b * NDIAGP_ * U1_;
    const float* EMb = EMD + (size_t)b * NDIAGP_ * U_;
    const float fblank = BLb[(size_t)dstar * U1_ + tl];

    const bool lane0 = (lane == 0);
    const bool tlpos = (tl > 0);
    const int  cap_d = tlpos ? dstar : il;

    float r  = 0.0f;
    float r0 = 1.0f;
    float Rc = 0.0f;
    float savedV = 1.0f, savedC = 0.0f;

    GLDS(0);
    __syncthreads();
    GLDS(1);
    CONV(0);
    __syncthreads();

    for (int c = 0; c < 5; ++c) {
        if (c + 2 <= 4) GLDS(c + 2);
        if (c + 1 <= 4) CONV(c + 1);
        if (wave == 0) { CHUNK_BODY(c); }
        __syncthreads();
    }

    if (wave == 0) {
        const int sl = tlpos ? (tl - 1) : 0;
        float sv = __int_as_float(
            __builtin_amdgcn_readlane(__float_as_int(savedV), sl));
        float sc = __int_as_float(
            __builtin_amdgcn_readlane(__float_as_int(savedC), 0));
        if (lane == 0)
            atomicAdd(sink, -(sc + log2f(sv) + fblank) * (LN2_ / B_));
    }
}

extern "C" void kernel_launch(void* const* d_in, const int* in_sizes, int n_in,
                              void* d_out, int out_size, void* d_ws, size_t ws_size,
                              hipStream_t stream)
{
    const float* enc     = (const float*)d_in[0];
    const float* dec     = (const float*)d_in[1];
    const int*   targets = (const int*)d_in[2];
    const int*   il      = (const int*)d_in[3];
    const int*   tl      = (const int*)d_in[4];
    float*       out     = (float*)d_out;

    float* edec = (float*)d_ws;                           // B*U1*V
    float* BLD  = edec + (size_t)B_ * U1_ * V_;           // B*NDIAGP*U1
    float* EMD  = BLD  + (size_t)B_ * NDIAGP_ * U1_;      // B*NDIAGP*U_
    float* scratch = EMD + (size_t)B_ * NDIAGP_ * U_;     // dead sink (1 float)

    const int n4 = B_ * U1_ * V_ / 4;
    k_exp<<<(n4 + 255) / 256, 256, 0, stream>>>(dec, edec, n4, out);
    k_logprobs<<<B_ * T_ / NT_, 256, 0, stream>>>(enc, dec, edec, targets, BLD, EMD);
    // MEASUREMENT: 4 replicas -> dead scratch; 5th -> real output.
    k_alpha<<<B_, 256, 0, stream>>>(BLD, EMD, il, tl, scratch);
    k_alpha<<<B_, 256, 0, stream>>>(BLD, EMD, il, tl, scratch);
    k_alpha<<<B_, 256, 0, stream>>>(BLD, EMD, il, tl, scratch);
    k_alpha<<<B_, 256, 0, stream>>>(BLD, EMD, il, tl, scratch);
    k_alpha<<<B_, 256, 0, stream>>>(BLD, EMD, il, tl, out);
}

// Round 16
// 44.546 us; speedup vs baseline: 2.9626x; 2.9626x over previous
//
#include <hip/hip_runtime.h>

#define B_ 8
#define T_ 256
#define U_ 64
#define U1_ 65
#define V_ 512
#define NDIAGP_ 336   // padded diagonal count (GLDS over-read stays in-bounds)
#define NT_ 2         // t-rows per k_logprobs block
#define CH_ 64        // diagonals per k_alpha chunk

#define LOG2E_ 1.4426950408889634f
#define LN2_   0.6931471805599453f

#if __has_builtin(__builtin_amdgcn_exp2f)
#define EXP2(x) __builtin_amdgcn_exp2f(x)
#else
#define EXP2(x) exp2f(x)
#endif

// ---------------------------------------------------------------------------
// Kernel 0: edec = exp(dec) (float4); thread 0 also zeroes the output scalar.
// ---------------------------------------------------------------------------
__global__ __launch_bounds__(256) void k_exp(const float* __restrict__ x,
                                             float* __restrict__ y, int n4,
                                             float* __restrict__ out)
{
    int i = blockIdx.x * blockDim.x + threadIdx.x;
    if (i == 0) out[0] = 0.0f;
    if (i < n4) {
        float4 v = ((const float4*)x)[i];
        float4 r;
        r.x = __expf(v.x); r.y = __expf(v.y);
        r.z = __expf(v.z); r.w = __expf(v.w);
        ((float4*)y)[i] = r;
    }
}

// ---------------------------------------------------------------------------
// DPP wave-sum: canonical GCN sequence; total lands in lane 63.
// row_shr steps use full masks (bound_ctrl zero-fills row starts);
// row_bcast:15 updates rows 1,3 only (0xa); row_bcast:31 rows 2,3 (0xc).
// ---------------------------------------------------------------------------
template <int CTRL, int RM>
__device__ __forceinline__ float dppadd(float x) {
    return x + __int_as_float(__builtin_amdgcn_update_dpp(
        0, __float_as_int(x), CTRL, RM, 0xf, true));
}
__device__ __forceinline__ float wave_sum64(float x) {
    x = dppadd<0x111, 0xf>(x);  // row_shr:1
    x = dppadd<0x112, 0xf>(x);  // row_shr:2
    x = dppadd<0x114, 0xf>(x);  // row_shr:4
    x = dppadd<0x118, 0xf>(x);  // row_shr:8
    x = dppadd<0x142, 0xa>(x);  // row_bcast:15 -> rows 1,3
    x = dppadd<0x143, 0xc>(x);  // row_bcast:31 -> rows 2,3
    return x;                    // lane 63 holds the full sum
}

// ---------------------------------------------------------------------------
// Kernel 1: block = (b, pair of t's). lse2[u] = log2( exp(enc_row) . edec_row[u] ).
// 1024 blocks (16 waves/CU) for TLP; DPP reduction (no LDS pipe); epilogue
// on lane 63. Diagonal-major log2-domain outputs:
//   BLD[b][t+u][u]  (stride 65) = (enc[0]+dec[u][0])*log2e     - lse2
//   EMD[b][t+u][u]  (stride 64) = (enc[tgt]+dec[u][tgt])*log2e - lse2
// ---------------------------------------------------------------------------
__global__ __launch_bounds__(256) void k_logprobs(
    const float* __restrict__ enc, const float* __restrict__ dec,
    const float* __restrict__ edec, const int* __restrict__ targets,
    float* __restrict__ BLD, float* __restrict__ EMD)
{
    const int blk  = blockIdx.x;           // 0 .. B_*T_/NT_ - 1 (1024)
    const int b    = blk % B_;             // XCD affinity with k_alpha
    const int tg   = blk / B_;
    const int t0   = tg * NT_;
    const int wave = threadIdx.x >> 6;
    const int lane = threadIdx.x & 63;

    float4 xe0[NT_], xe1[NT_];
    float  er0[NT_];
    #pragma unroll
    for (int j = 0; j < NT_; ++j) {
        const float* erow = enc + (size_t)(b * T_ + t0 + j) * V_;
        float4 e0 = *(const float4*)(erow + lane * 4);
        float4 e1 = *(const float4*)(erow + 256 + lane * 4);
        xe0[j].x = __expf(e0.x); xe0[j].y = __expf(e0.y);
        xe0[j].z = __expf(e0.z); xe0[j].w = __expf(e0.w);
        xe1[j].x = __expf(e1.x); xe1[j].y = __expf(e1.y);
        xe1[j].z = __expf(e1.z); xe1[j].w = __expf(e1.w);
        er0[j] = erow[0];
    }

    for (int u = wave; u <= U_; u += 4) {
        const float* xdrow = edec + (size_t)(b * U1_ + u) * V_;
        float4 d0 = *(const float4*)(xdrow + lane * 4);
        float4 d1 = *(const float4*)(xdrow + 256 + lane * 4);

        float s[NT_];
        #pragma unroll
        for (int j = 0; j < NT_; ++j) {
            float sA = xe0[j].x * d0.x;
            float sB = xe1[j].x * d1.x;
            sA = fmaf(xe0[j].y, d0.y, sA);  sB = fmaf(xe1[j].y, d1.y, sB);
            sA = fmaf(xe0[j].z, d0.z, sA);  sB = fmaf(xe1[j].z, d1.z, sB);
            sA = fmaf(xe0[j].w, d0.w, sA);  sB = fmaf(xe1[j].w, d1.w, sB);
            s[j] = sA + sB;
        }

        #pragma unroll
        for (int j = 0; j < NT_; ++j)
            s[j] = wave_sum64(s[j]);

        if (lane == 63) {
            const float* dr = dec + (size_t)(b * U1_ + u) * V_;
            const float d_blank = dr[0];
            int   tgt = 0;
            float d_tgt = 0.0f;
            if (u < U_) { tgt = targets[b * U_ + u]; d_tgt = dr[tgt]; }
            #pragma unroll
            for (int j = 0; j < NT_; ++j) {
                const int t  = t0 + j;
                const int dg = t + u;
                const float lse2 = log2f(s[j]);
                BLD[((size_t)b * NDIAGP_ + dg) * U1_ + u] =
                    (er0[j] + d_blank) * LOG2E_ - lse2;
                if (u < U_) {
                    const float* er = enc + (size_t)(b * T_ + t) * V_;
                    EMD[((size_t)b * NDIAGP_ + dg) * U_ + u] =
                        (er[tgt] + d_tgt) * LOG2E_ - lse2;
                }
            }
        }
    }
}

// ---------------------------------------------------------------------------
// Kernel 2: alpha recursion (R14, unchanged): linear domain vs. log2 ref,
// renorm every 8 diagonals, branchless capture, 3-stage LDS pipeline.
// ---------------------------------------------------------------------------
__device__ __forceinline__ float wshr1(float x) {
    return __int_as_float(__builtin_amdgcn_update_dpp(
        0, __float_as_int(x), 0x138, 0xf, 0xf, true));
}
template <int CTRL>
__device__ __forceinline__ float dppmax(float x) {
    return fmaxf(x, __int_as_float(__builtin_amdgcn_update_dpp(
        0, __float_as_int(x), CTRL, 0xf, 0xf, false)));
}
__device__ __forceinline__ float wave_max64(float x) {
    x = dppmax<0x111>(x);  // row_shr:1
    x = dppmax<0x112>(x);  // row_shr:2
    x = dppmax<0x114>(x);  // row_shr:4
    x = dppmax<0x118>(x);  // row_shr:8
    x = dppmax<0x142>(x);  // row_bcast:15
    x = dppmax<0x143>(x);  // row_bcast:31
    return __int_as_float(__builtin_amdgcn_readlane(__float_as_int(x), 63));
}

#define GLDS(c_) do {                                                           \
    if (wave > 0) {                                                             \
        const float* gbl = BLb + (size_t)(c_) * CH_ * U1_;                      \
        const float* gem = EMb + (size_t)(c_) * CH_ * U_;                       \
        float* lbl_ = sRBL[(c_) & 1];                                           \
        float* lem_ = sREM[(c_) & 1];                                           \
        for (int i = wave - 1; i < 17; i += 3)                                  \
            __builtin_amdgcn_global_load_lds(                                   \
                (const __attribute__((address_space(1))) void*)(gbl + i * 256 + lane * 4), \
                (__attribute__((address_space(3))) void*)(lbl_ + i * 256), 16, 0, 0);      \
        for (int i = wave - 1; i < 16; i += 3)                                  \
            __builtin_amdgcn_global_load_lds(                                   \
                (const __attribute__((address_space(1))) void*)(gem + i * 256 + lane * 4), \
                (__attribute__((address_space(3))) void*)(lem_ + i * 256), 16, 0, 0);      \
    }                                                                           \
} while (0)

#define CONV(c_) do {                                                           \
    if (wave > 0) {                                                             \
        const float* rbl = sRBL[(c_) & 1];                                      \
        const float* rem = sREM[(c_) & 1];                                      \
        float2* pv_ = sPV[(c_) & 1];                                            \
        float*  pc_ = sPC[(c_) & 1];                                            \
        _Pragma("unroll 4")                                                     \
        for (int i = wave - 1; i < CH_; i += 3) {                               \
            const float bl = rbl[i * U1_ + lane + 1];                           \
            const float em = rem[i * U_ + lane];                                \
            const float pc = ((c_) == 4) ? rbl[i * U1_ + i + 1]                 \
                                         : rbl[i * U1_];                        \
            float vb = fminf(bl - pc, 126.0f);                                  \
            float ve = fminf(em - pc, 126.0f);                                  \
            if ((c_) == 0 && lane == i) vb = -200.0f;                           \
            if ((c_) == 4 && lane <= i) { vb = -200.0f; ve = -200.0f; }         \
            pv_[i * 64 + lane] = make_float2(EXP2(vb), EXP2(ve));               \
            if (lane == 0) pc_[i] = pc;                                         \
        }                                                                       \
    }                                                                           \
} while (0)

#define LOADG(PV, PC, g_) do {                                                  \
    _Pragma("unroll")                                                           \
    for (int j = 0; j < 8; ++j) {                                               \
        PV[j] = pvb[(8 * (g_) + j) * 64 + lane];                                \
        PC[j] = pcb[8 * (g_) + j];                                              \
    }                                                                           \
} while (0)

#define COMPG(PV, PC, g_) do {                                                  \
    _Pragma("unroll")                                                           \
    for (int j = 0; j < 8; ++j) {                                               \
        const int d = d0 + 8 * (g_) + j + 1;                                    \
        float sr = wshr1(r);                                                    \
        sr = lane0 ? r0 : sr;                                                   \
        r = fmaf(sr, PV[j].y, r * PV[j].x);                                     \
        const bool cap = (d == cap_d);                                          \
        savedV = cap ? (tlpos ? r : r0) : savedV;                               \
        savedC = cap ? (tlpos ? Rc + PC[j] : Rc) : savedC;                      \
        Rc += PC[j];                                                            \
    }                                                                           \
    {                                                                           \
        float m = wave_max64(r);                                                \
        int mb = __float_as_int(m);                                             \
        int e = (mb >> 23) - 127;                                               \
        e = (mb >= 0x00800000) ? e : 0;                                         \
        float sc = __int_as_float((127 - e) << 23);                             \
        r *= sc;  r0 *= sc;  Rc += (float)e;                                    \
    }                                                                           \
} while (0)

#define CHUNK_BODY(c_) do {                                                     \
    const float2* pvb = sPV[(c_) & 1];                                          \
    const float*  pcb = sPC[(c_) & 1];                                          \
    const int d0 = CH_ * (c_);                                                  \
    float2 pvA[8], pvB[8];                                                      \
    float  pcA[8], pcB[8];                                                      \
    LOADG(pvA, pcA, 0);                                                         \
    for (int g = 0; g < 8; g += 2) {                                            \
        LOADG(pvB, pcB, g + 1);                                                 \
        COMPG(pvA, pcA, g);                                                     \
        if (g + 2 < 8) LOADG(pvA, pcA, g + 2);                                  \
        COMPG(pvB, pcB, g + 1);                                                 \
    }                                                                           \
} while (0)

__global__ __launch_bounds__(256) void k_alpha(
    const float* __restrict__ BLD, const float* __restrict__ EMD,
    const int* __restrict__ il_, const int* __restrict__ tl_,
    float* __restrict__ sink)
{
    __shared__ __align__(16) float  sRBL[2][17 * 256];
    __shared__ __align__(16) float  sREM[2][16 * 256];
    __shared__ __align__(16) float2 sPV[2][CH_ * 64];
    __shared__ float sPC[2][CH_];

    const int b    = blockIdx.x;
    const int wave = threadIdx.x >> 6;
    const int lane = threadIdx.x & 63;
    const int il   = il_[b];
    const int tl   = tl_[b];
    const int dstar = il - 1 + tl;
    const float* BLb = BLD + (size_t)b * NDIAGP_ * U1_;
    const float* EMb = EMD + (size_t)b * NDIAGP_ * U_;
    const float fblank = BLb[(size_t)dstar * U1_ + tl];

    const bool lane0 = (lane == 0);
    const bool tlpos = (tl > 0);
    const int  cap_d = tlpos ? dstar : il;

    float r  = 0.0f;
    float r0 = 1.0f;
    float Rc = 0.0f;
    float savedV = 1.0f, savedC = 0.0f;

    GLDS(0);
    __syncthreads();
    GLDS(1);
    CONV(0);
    __syncthreads();

    for (int c = 0; c < 5; ++c) {
        if (c + 2 <= 4) GLDS(c + 2);
        if (c + 1 <= 4) CONV(c + 1);
        if (wave == 0) { CHUNK_BODY(c); }
        __syncthreads();
    }

    if (wave == 0) {
        const int sl = tlpos ? (tl - 1) : 0;
        float sv = __int_as_float(
            __builtin_amdgcn_readlane(__float_as_int(savedV), sl));
        float sc = __int_as_float(
            __builtin_amdgcn_readlane(__float_as_int(savedC), 0));
        if (lane == 0)
            atomicAdd(sink, -(sc + log2f(sv) + fblank) * (LN2_ / B_));
    }
}

extern "C" void kernel_launch(void* const* d_in, const int* in_sizes, int n_in,
                              void* d_out, int out_size, void* d_ws, size_t ws_size,
                              hipStream_t stream)
{
    const float* enc     = (const float*)d_in[0];
    const float* dec     = (const float*)d_in[1];
    const int*   targets = (const int*)d_in[2];
    const int*   il      = (const int*)d_in[3];
    const int*   tl      = (const int*)d_in[4];
    float*       out     = (float*)d_out;

    float* edec = (float*)d_ws;                           // B*U1*V
    float* BLD  = edec + (size_t)B_ * U1_ * V_;           // B*NDIAGP*U1
    float* EMD  = BLD  + (size_t)B_ * NDIAGP_ * U1_;      // B*NDIAGP*U_

    const int n4 = B_ * U1_ * V_ / 4;
    k_exp<<<(n4 + 255) / 256, 256, 0, stream>>>(dec, edec, n4, out);
    k_logprobs<<<B_ * T_ / NT_, 256, 0, stream>>>(enc, dec, edec, targets, BLD, EMD);
    k_alpha<<<B_, 256, 0, stream>>>(BLD, EMD, il, tl, out);
}

// Round 17
// 40.499 us; speedup vs baseline: 3.2587x; 1.0999x over previous
//
#include <hip/hip_runtime.h>

#define B_ 8
#define T_ 256
#define U_ 64
#define U1_ 65
#define V_ 512
#define NDIAGP_ 336   // padded diagonal count (GLDS over-read stays in-bounds)
#define NT_ 2         // t-rows per k_logprobs block
#define CH_ 64        // diagonals per k_alpha chunk
#define AW_ 8         // waves per k_alpha block (1 consumer + 7 producers)

#define LOG2E_ 1.4426950408889634f
#define LN2_   0.6931471805599453f

#if __has_builtin(__builtin_amdgcn_exp2f)
#define EXP2(x) __builtin_amdgcn_exp2f(x)
#else
#define EXP2(x) exp2f(x)
#endif

// ---------------------------------------------------------------------------
// Kernel 0: edec = exp(dec) (float4); thread 0 also zeroes the output scalar.
// ---------------------------------------------------------------------------
__global__ __launch_bounds__(256) void k_exp(const float* __restrict__ x,
                                             float* __restrict__ y, int n4,
                                             float* __restrict__ out)
{
    int i = blockIdx.x * blockDim.x + threadIdx.x;
    if (i == 0) out[0] = 0.0f;
    if (i < n4) {
        float4 v = ((const float4*)x)[i];
        float4 r;
        r.x = __expf(v.x); r.y = __expf(v.y);
        r.z = __expf(v.z); r.w = __expf(v.w);
        ((float4*)y)[i] = r;
    }
}

// ---------------------------------------------------------------------------
// DPP wave-sum: canonical GCN sequence; total lands in lane 63.
// ---------------------------------------------------------------------------
template <int CTRL, int RM>
__device__ __forceinline__ float dppadd(float x) {
    return x + __int_as_float(__builtin_amdgcn_update_dpp(
        0, __float_as_int(x), CTRL, RM, 0xf, true));
}
__device__ __forceinline__ float wave_sum64(float x) {
    x = dppadd<0x111, 0xf>(x);  // row_shr:1
    x = dppadd<0x112, 0xf>(x);  // row_shr:2
    x = dppadd<0x114, 0xf>(x);  // row_shr:4
    x = dppadd<0x118, 0xf>(x);  // row_shr:8
    x = dppadd<0x142, 0xa>(x);  // row_bcast:15 -> rows 1,3
    x = dppadd<0x143, 0xc>(x);  // row_bcast:31 -> rows 2,3
    return x;                    // lane 63 holds the full sum
}

// ---------------------------------------------------------------------------
// Kernel 1 (unchanged from R16): block = (b, pair of t's).
// lse2[u] = log2( exp(enc_row) . edec_row[u] ); diagonal-major log2 outputs.
// ---------------------------------------------------------------------------
__global__ __launch_bounds__(256) void k_logprobs(
    const float* __restrict__ enc, const float* __restrict__ dec,
    const float* __restrict__ edec, const int* __restrict__ targets,
    float* __restrict__ BLD, float* __restrict__ EMD)
{
    const int blk  = blockIdx.x;           // 0 .. B_*T_/NT_ - 1 (1024)
    const int b    = blk % B_;             // XCD affinity with k_alpha
    const int tg   = blk / B_;
    const int t0   = tg * NT_;
    const int wave = threadIdx.x >> 6;
    const int lane = threadIdx.x & 63;

    float4 xe0[NT_], xe1[NT_];
    float  er0[NT_];
    #pragma unroll
    for (int j = 0; j < NT_; ++j) {
        const float* erow = enc + (size_t)(b * T_ + t0 + j) * V_;
        float4 e0 = *(const float4*)(erow + lane * 4);
        float4 e1 = *(const float4*)(erow + 256 + lane * 4);
        xe0[j].x = __expf(e0.x); xe0[j].y = __expf(e0.y);
        xe0[j].z = __expf(e0.z); xe0[j].w = __expf(e0.w);
        xe1[j].x = __expf(e1.x); xe1[j].y = __expf(e1.y);
        xe1[j].z = __expf(e1.z); xe1[j].w = __expf(e1.w);
        er0[j] = erow[0];
    }

    for (int u = wave; u <= U_; u += 4) {
        const float* xdrow = edec + (size_t)(b * U1_ + u) * V_;
        float4 d0 = *(const float4*)(xdrow + lane * 4);
        float4 d1 = *(const float4*)(xdrow + 256 + lane * 4);

        float s[NT_];
        #pragma unroll
        for (int j = 0; j < NT_; ++j) {
            float sA = xe0[j].x * d0.x;
            float sB = xe1[j].x * d1.x;
            sA = fmaf(xe0[j].y, d0.y, sA);  sB = fmaf(xe1[j].y, d1.y, sB);
            sA = fmaf(xe0[j].z, d0.z, sA);  sB = fmaf(xe1[j].z, d1.z, sB);
            sA = fmaf(xe0[j].w, d0.w, sA);  sB = fmaf(xe1[j].w, d1.w, sB);
            s[j] = sA + sB;
        }

        #pragma unroll
        for (int j = 0; j < NT_; ++j)
            s[j] = wave_sum64(s[j]);

        if (lane == 63) {
            const float* dr = dec + (size_t)(b * U1_ + u) * V_;
            const float d_blank = dr[0];
            int   tgt = 0;
            float d_tgt = 0.0f;
            if (u < U_) { tgt = targets[b * U_ + u]; d_tgt = dr[tgt]; }
            #pragma unroll
            for (int j = 0; j < NT_; ++j) {
                const int t  = t0 + j;
                const int dg = t + u;
                const float lse2 = log2f(s[j]);
                BLD[((size_t)b * NDIAGP_ + dg) * U1_ + u] =
                    (er0[j] + d_blank) * LOG2E_ - lse2;
                if (u < U_) {
                    const float* er = enc + (size_t)(b * T_ + t) * V_;
                    EMD[((size_t)b * NDIAGP_ + dg) * U_ + u] =
                        (er[tgt] + d_tgt) * LOG2E_ - lse2;
                }
            }
        }
    }
}

// ---------------------------------------------------------------------------
// Kernel 2: alpha recursion (math identical to R14/R16). 8 waves: wave 0
// consumes; waves 1-7 produce. CONV output packed as float4 pairs so the
// consumer reads 4x ds_read_b128 + 2 uniform b128 per 8 diagonals.
// ---------------------------------------------------------------------------
__device__ __forceinline__ float wshr1(float x) {
    return __int_as_float(__builtin_amdgcn_update_dpp(
        0, __float_as_int(x), 0x138, 0xf, 0xf, true));
}
template <int CTRL>
__device__ __forceinline__ float dppmax(float x) {
    return fmaxf(x, __int_as_float(__builtin_amdgcn_update_dpp(
        0, __float_as_int(x), CTRL, 0xf, 0xf, false)));
}
__device__ __forceinline__ float wave_max64(float x) {
    x = dppmax<0x111>(x);  // row_shr:1
    x = dppmax<0x112>(x);  // row_shr:2
    x = dppmax<0x114>(x);  // row_shr:4
    x = dppmax<0x118>(x);  // row_shr:8
    x = dppmax<0x142>(x);  // row_bcast:15
    x = dppmax<0x143>(x);  // row_bcast:31
    return __int_as_float(__builtin_amdgcn_readlane(__float_as_int(x), 63));
}

#define GLDS(c_) do {                                                           \
    if (wave > 0) {                                                             \
        const float* gbl = BLb + (size_t)(c_) * CH_ * U1_;                      \
        const float* gem = EMb + (size_t)(c_) * CH_ * U_;                       \
        float* lbl_ = sRBL[(c_) & 1];                                           \
        float* lem_ = sREM[(c_) & 1];                                           \
        for (int i = wave - 1; i < 17; i += 7)                                  \
            __builtin_amdgcn_global_load_lds(                                   \
                (const __attribute__((address_space(1))) void*)(gbl + i * 256 + lane * 4), \
                (__attribute__((address_space(3))) void*)(lbl_ + i * 256), 16, 0, 0);      \
        for (int i = wave - 1; i < 16; i += 7)                                  \
            __builtin_amdgcn_global_load_lds(                                   \
                (const __attribute__((address_space(1))) void*)(gem + i * 256 + lane * 4), \
                (__attribute__((address_space(3))) void*)(lem_ + i * 256), 16, 0, 0);      \
    }                                                                           \
} while (0)

// CONV row i of chunk c_: pbv = 2^(BL[diag][l+1]-pc), pev = 2^(EM[diag][l]-pc).
// Written as float2 half of the float4 pair row (pair i>>1, half i&1).
#define CONV(c_) do {                                                           \
    if (wave > 0) {                                                             \
        const float* rbl = sRBL[(c_) & 1];                                      \
        const float* rem = sREM[(c_) & 1];                                      \
        float4* pv_ = sPV[(c_) & 1];                                            \
        float*  pc_ = sPC[(c_) & 1];                                            \
        _Pragma("unroll 3")                                                     \
        for (int i = wave - 1; i < CH_; i += 7) {                               \
            const float bl = rbl[i * U1_ + lane + 1];                           \
            const float em = rem[i * U_ + lane];                                \
            const float pc = ((c_) == 4) ? rbl[i * U1_ + i + 1]                 \
                                         : rbl[i * U1_];                        \
            float vb = fminf(bl - pc, 126.0f);                                  \
            float ve = fminf(em - pc, 126.0f);                                  \
            if ((c_) == 0 && lane == i) vb = -200.0f;                           \
            if ((c_) == 4 && lane <= i) { vb = -200.0f; ve = -200.0f; }         \
            ((float2*)&pv_[(i >> 1) * 64 + lane])[i & 1] =                      \
                make_float2(EXP2(vb), EXP2(ve));                                \
            if (lane == 0) pc_[i] = pc;                                         \
        }                                                                       \
    }                                                                           \
} while (0)

// Group g (8 diagonals): 4 float4 pair-rows + 2 uniform float4 pc quads.
#define LOADG(PV, PCQ, g_) do {                                                 \
    _Pragma("unroll")                                                           \
    for (int k = 0; k < 4; ++k)                                                 \
        PV[k] = pvb[(4 * (g_) + k) * 64 + lane];                                \
    PCQ[0] = pcb4[2 * (g_)];                                                    \
    PCQ[1] = pcb4[2 * (g_) + 1];                                                \
} while (0)

#define PCSEL(PCQ, j_) ((j_) < 4 ? ((j_) == 0 ? PCQ[0].x : (j_) == 1 ? PCQ[0].y \
                                  : (j_) == 2 ? PCQ[0].z : PCQ[0].w)            \
                                 : ((j_) == 4 ? PCQ[1].x : (j_) == 5 ? PCQ[1].y \
                                  : (j_) == 6 ? PCQ[1].z : PCQ[1].w))

#define COMPG(PV, PCQ, g_) do {                                                 \
    _Pragma("unroll")                                                           \
    for (int j = 0; j < 8; ++j) {                                               \
        const int d = d0 + 8 * (g_) + j + 1;                                    \
        const float pbv = (j & 1) ? PV[j >> 1].z : PV[j >> 1].x;                \
        const float pev = (j & 1) ? PV[j >> 1].w : PV[j >> 1].y;                \
        const float pcj = PCSEL(PCQ, j);                                        \
        float sr = wshr1(r);                                                    \
        sr = lane0 ? r0 : sr;                                                   \
        r = fmaf(sr, pev, r * pbv);                                             \
        const bool cap = (d == cap_d);                                          \
        savedV = cap ? (tlpos ? r : r0) : savedV;                               \
        savedC = cap ? (tlpos ? Rc + pcj : Rc) : savedC;                        \
        Rc += pcj;                                                              \
    }                                                                           \
    {                                                                           \
        float m = wave_max64(r);                                                \
        int mb = __float_as_int(m);                                             \
        int e = (mb >> 23) - 127;                                               \
        e = (mb >= 0x00800000) ? e : 0;                                         \
        float sc = __int_as_float((127 - e) << 23);                             \
        r *= sc;  r0 *= sc;  Rc += (float)e;                                    \
    }                                                                           \
} while (0)

#define CHUNK_BODY(c_) do {                                                     \
    const float4* pvb  = sPV[(c_) & 1];                                         \
    const float4* pcb4 = (const float4*)sPC[(c_) & 1];                          \
    const int d0 = CH_ * (c_);                                                  \
    float4 pvA[4], pvB[4];                                                      \
    float4 pcA[2], pcB[2];                                                      \
    LOADG(pvA, pcA, 0);                                                         \
    for (int g = 0; g < 8; g += 2) {                                            \
        LOADG(pvB, pcB, g + 1);                                                 \
        COMPG(pvA, pcA, g);                                                     \
        if (g + 2 < 8) LOADG(pvA, pcA, g + 2);                                  \
        COMPG(pvB, pcB, g + 1);                                                 \
    }                                                                           \
} while (0)

__global__ __launch_bounds__(512) void k_alpha(
    const float* __restrict__ BLD, const float* __restrict__ EMD,
    const int* __restrict__ il_, const int* __restrict__ tl_,
    float* __restrict__ sink)
{
    __shared__ __align__(16) float  sRBL[2][17 * 256];   // raw BL (34 KB)
    __shared__ __align__(16) float  sREM[2][16 * 256];   // raw EM (32 KB)
    __shared__ __align__(16) float4 sPV[2][32 * 64];     // packed pairs (64 KB)
    __shared__ __align__(16) float  sPC[2][CH_];         // refs (512 B)

    const int b    = blockIdx.x;
    const int wave = threadIdx.x >> 6;
    const int lane = threadIdx.x & 63;
    const int il   = il_[b];
    const int tl   = tl_[b];
    const int dstar = il - 1 + tl;
    const float* BLb = BLD + (size_t)b * NDIAGP_ * U1_;
    const float* EMb = EMD + (size_t)b * NDIAGP_ * U_;
    const float fblank = BLb[(size_t)dstar * U1_ + tl];

    const bool lane0 = (lane == 0);
    const bool tlpos = (tl > 0);
    const int  cap_d = tlpos ? dstar : il;

    float r  = 0.0f;
    float r0 = 1.0f;
    float Rc = 0.0f;
    float savedV = 1.0f, savedC = 0.0f;

    GLDS(0);
    __syncthreads();
    GLDS(1);
    CONV(0);
    __syncthreads();

    for (int c = 0; c < 5; ++c) {
        if (c + 2 <= 4) GLDS(c + 2);
        if (c + 1 <= 4) CONV(c + 1);
        if (wave == 0) { CHUNK_BODY(c); }
        __syncthreads();
    }

    if (wave == 0) {
        const int sl = tlpos ? (tl - 1) : 0;
        float sv = __int_as_float(
            __builtin_amdgcn_readlane(__float_as_int(savedV), sl));
        float sc = __int_as_float(
            __builtin_amdgcn_readlane(__float_as_int(savedC), 0));
        if (lane == 0)
            atomicAdd(sink, -(sc + log2f(sv) + fblank) * (LN2_ / B_));
    }
}

extern "C" void kernel_launch(void* const* d_in, const int* in_sizes, int n_in,
                              void* d_out, int out_size, void* d_ws, size_t ws_size,
                              hipStream_t stream)
{
    const float* enc     = (const float*)d_in[0];
    const float* dec     = (const float*)d_in[1];
    const int*   targets = (const int*)d_in[2];
    const int*   il      = (const int*)d_in[3];
    const int*   tl      = (const int*)d_in[4];
    float*       out     = (float*)d_out;

    float* edec = (float*)d_ws;                           // B*U1*V
    float* BLD  = edec + (size_t)B_ * U1_ * V_;           // B*NDIAGP*U1
    float* EMD  = BLD  + (size_t)B_ * NDIAGP_ * U1_;      // B*NDIAGP*U_

    const int n4 = B_ * U1_ * V_ / 4;
    k_exp<<<(n4 + 255) / 256, 256, 0, stream>>>(dec, edec, n4, out);
    k_logprobs<<<B_ * T_ / NT_, 256, 0, stream>>>(enc, dec, edec, targets, BLD, EMD);
    k_alpha<<<B_, 512, 0, stream>>>(BLD, EMD, il, tl, out);
}

// Round 18
// 37.385 us; speedup vs baseline: 3.5301x; 1.0833x over previous
//
#include <hip/hip_runtime.h>

#define B_ 8
#define T_ 256
#define U_ 64
#define U1_ 65
#define V_ 512
#define NDIAGP_ 336   // padded diagonal count (GLDS over-read stays in-bounds)
#define NT_ 2         // t-rows per k_logprobs block
#define CH_ 64        // diagonals per k_alpha chunk

#define LOG2E_ 1.4426950408889634f
#define LN2_   0.6931471805599453f

#if __has_builtin(__builtin_amdgcn_exp2f)
#define EXP2(x) __builtin_amdgcn_exp2f(x)
#else
#define EXP2(x) exp2f(x)
#endif

// ---------------------------------------------------------------------------
// DPP wave-sum: canonical GCN sequence; total lands in lane 63.
// ---------------------------------------------------------------------------
template <int CTRL, int RM>
__device__ __forceinline__ float dppadd(float x) {
    return x + __int_as_float(__builtin_amdgcn_update_dpp(
        0, __float_as_int(x), CTRL, RM, 0xf, true));
}
__device__ __forceinline__ float wave_sum64(float x) {
    x = dppadd<0x111, 0xf>(x);  // row_shr:1
    x = dppadd<0x112, 0xf>(x);  // row_shr:2
    x = dppadd<0x114, 0xf>(x);  // row_shr:4
    x = dppadd<0x118, 0xf>(x);  // row_shr:8
    x = dppadd<0x142, 0xa>(x);  // row_bcast:15 -> rows 1,3
    x = dppadd<0x143, 0xc>(x);  // row_bcast:31 -> rows 2,3
    return x;                    // lane 63 holds the full sum
}

// ---------------------------------------------------------------------------
// Kernel 1: block = (b, pair of t's). Computes exp(dec) INLINE (no k_exp
// kernel, no edec round-trip). lse2[u] = log2( Σ_v exp(enc_v) * exp(dec_v) ).
// Diagonal-major log2-domain outputs:
//   BLD[b][t+u][u]  (stride 65) = (enc[0]+dec[u][0])*log2e     - lse2
//   EMD[b][t+u][u]  (stride 64) = (enc[tgt]+dec[u][tgt])*log2e - lse2
// Block 0 also zeroes the output scalar (stream-ordered before k_alpha).
// ---------------------------------------------------------------------------
__global__ __launch_bounds__(256) void k_logprobs(
    const float* __restrict__ enc, const float* __restrict__ dec,
    const int* __restrict__ targets,
    float* __restrict__ BLD, float* __restrict__ EMD,
    float* __restrict__ out)
{
    const int blk  = blockIdx.x;           // 0 .. B_*T_/NT_ - 1 (1024)
    const int b    = blk % B_;             // XCD affinity with k_alpha
    const int tg   = blk / B_;
    const int t0   = tg * NT_;
    const int wave = threadIdx.x >> 6;
    const int lane = threadIdx.x & 63;

    if (blk == 0 && threadIdx.x == 0) out[0] = 0.0f;

    float4 xe0[NT_], xe1[NT_];
    float  er0[NT_];
    #pragma unroll
    for (int j = 0; j < NT_; ++j) {
        const float* erow = enc + (size_t)(b * T_ + t0 + j) * V_;
        float4 e0 = *(const float4*)(erow + lane * 4);
        float4 e1 = *(const float4*)(erow + 256 + lane * 4);
        xe0[j].x = __expf(e0.x); xe0[j].y = __expf(e0.y);
        xe0[j].z = __expf(e0.z); xe0[j].w = __expf(e0.w);
        xe1[j].x = __expf(e1.x); xe1[j].y = __expf(e1.y);
        xe1[j].z = __expf(e1.z); xe1[j].w = __expf(e1.w);
        er0[j] = erow[0];
    }

    for (int u = wave; u <= U_; u += 4) {
        const float* drow = dec + (size_t)(b * U1_ + u) * V_;
        float4 d0 = *(const float4*)(drow + lane * 4);
        float4 d1 = *(const float4*)(drow + 256 + lane * 4);
        d0.x = __expf(d0.x); d0.y = __expf(d0.y);
        d0.z = __expf(d0.z); d0.w = __expf(d0.w);
        d1.x = __expf(d1.x); d1.y = __expf(d1.y);
        d1.z = __expf(d1.z); d1.w = __expf(d1.w);

        float s[NT_];
        #pragma unroll
        for (int j = 0; j < NT_; ++j) {
            float sA = xe0[j].x * d0.x;
            float sB = xe1[j].x * d1.x;
            sA = fmaf(xe0[j].y, d0.y, sA);  sB = fmaf(xe1[j].y, d1.y, sB);
            sA = fmaf(xe0[j].z, d0.z, sA);  sB = fmaf(xe1[j].z, d1.z, sB);
            sA = fmaf(xe0[j].w, d0.w, sA);  sB = fmaf(xe1[j].w, d1.w, sB);
            s[j] = sA + sB;
        }

        #pragma unroll
        for (int j = 0; j < NT_; ++j)
            s[j] = wave_sum64(s[j]);

        if (lane == 63) {
            const float d_blank = drow[0];
            int   tgt = 0;
            float d_tgt = 0.0f;
            if (u < U_) { tgt = targets[b * U_ + u]; d_tgt = drow[tgt]; }
            #pragma unroll
            for (int j = 0; j < NT_; ++j) {
                const int t  = t0 + j;
                const int dg = t + u;
                const float lse2 = log2f(s[j]);
                BLD[((size_t)b * NDIAGP_ + dg) * U1_ + u] =
                    (er0[j] + d_blank) * LOG2E_ - lse2;
                if (u < U_) {
                    const float* er = enc + (size_t)(b * T_ + t) * V_;
                    EMD[((size_t)b * NDIAGP_ + dg) * U_ + u] =
                        (er[tgt] + d_tgt) * LOG2E_ - lse2;
                }
            }
        }
    }
}

// ---------------------------------------------------------------------------
// Kernel 2: alpha recursion (R17, unchanged). 8 waves: wave 0 consumes;
// waves 1-7 produce (GLDS raw c+2, CONV c+1 packed float4 pairs).
// ---------------------------------------------------------------------------
__device__ __forceinline__ float wshr1(float x) {
    return __int_as_float(__builtin_amdgcn_update_dpp(
        0, __float_as_int(x), 0x138, 0xf, 0xf, true));
}
template <int CTRL>
__device__ __forceinline__ float dppmax(float x) {
    return fmaxf(x, __int_as_float(__builtin_amdgcn_update_dpp(
        0, __float_as_int(x), CTRL, 0xf, 0xf, false)));
}
__device__ __forceinline__ float wave_max64(float x) {
    x = dppmax<0x111>(x);  // row_shr:1
    x = dppmax<0x112>(x);  // row_shr:2
    x = dppmax<0x114>(x);  // row_shr:4
    x = dppmax<0x118>(x);  // row_shr:8
    x = dppmax<0x142>(x);  // row_bcast:15
    x = dppmax<0x143>(x);  // row_bcast:31
    return __int_as_float(__builtin_amdgcn_readlane(__float_as_int(x), 63));
}

#define GLDS(c_) do {                                                           \
    if (wave > 0) {                                                             \
        const float* gbl = BLb + (size_t)(c_) * CH_ * U1_;                      \
        const float* gem = EMb + (size_t)(c_) * CH_ * U_;                       \
        float* lbl_ = sRBL[(c_) & 1];                                           \
        float* lem_ = sREM[(c_) & 1];                                           \
        for (int i = wave - 1; i < 17; i += 7)                                  \
            __builtin_amdgcn_global_load_lds(                                   \
                (const __attribute__((address_space(1))) void*)(gbl + i * 256 + lane * 4), \
                (__attribute__((address_space(3))) void*)(lbl_ + i * 256), 16, 0, 0);      \
        for (int i = wave - 1; i < 16; i += 7)                                  \
            __builtin_amdgcn_global_load_lds(                                   \
                (const __attribute__((address_space(1))) void*)(gem + i * 256 + lane * 4), \
                (__attribute__((address_space(3))) void*)(lem_ + i * 256), 16, 0, 0);      \
    }                                                                           \
} while (0)

#define CONV(c_) do {                                                           \
    if (wave > 0) {                                                             \
        const float* rbl = sRBL[(c_) & 1];                                      \
        const float* rem = sREM[(c_) & 1];                                      \
        float4* pv_ = sPV[(c_) & 1];                                            \
        float*  pc_ = sPC[(c_) & 1];                                            \
        _Pragma("unroll 3")                                                     \
        for (int i = wave - 1; i < CH_; i += 7) {                               \
            const float bl = rbl[i * U1_ + lane + 1];                           \
            const float em = rem[i * U_ + lane];                                \
            const float pc = ((c_) == 4) ? rbl[i * U1_ + i + 1]                 \
                                         : rbl[i * U1_];                        \
            float vb = fminf(bl - pc, 126.0f);                                  \
            float ve = fminf(em - pc, 126.0f);                                  \
            if ((c_) == 0 && lane == i) vb = -200.0f;                           \
            if ((c_) == 4 && lane <= i) { vb = -200.0f; ve = -200.0f; }         \
            ((float2*)&pv_[(i >> 1) * 64 + lane])[i & 1] =                      \
                make_float2(EXP2(vb), EXP2(ve));                                \
            if (lane == 0) pc_[i] = pc;                                         \
        }                                                                       \
    }                                                                           \
} while (0)

#define LOADG(PV, PCQ, g_) do {                                                 \
    _Pragma("unroll")                                                           \
    for (int k = 0; k < 4; ++k)                                                 \
        PV[k] = pvb[(4 * (g_) + k) * 64 + lane];                                \
    PCQ[0] = pcb4[2 * (g_)];                                                    \
    PCQ[1] = pcb4[2 * (g_) + 1];                                                \
} while (0)

#define PCSEL(PCQ, j_) ((j_) < 4 ? ((j_) == 0 ? PCQ[0].x : (j_) == 1 ? PCQ[0].y \
                                  : (j_) == 2 ? PCQ[0].z : PCQ[0].w)            \
                                 : ((j_) == 4 ? PCQ[1].x : (j_) == 5 ? PCQ[1].y \
                                  : (j_) == 6 ? PCQ[1].z : PCQ[1].w))

#define COMPG(PV, PCQ, g_) do {                                                 \
    _Pragma("unroll")                                                           \
    for (int j = 0; j < 8; ++j) {                                               \
        const int d = d0 + 8 * (g_) + j + 1;                                    \
        const float pbv = (j & 1) ? PV[j >> 1].z : PV[j >> 1].x;                \
        const float pev = (j & 1) ? PV[j >> 1].w : PV[j >> 1].y;                \
        const float pcj = PCSEL(PCQ, j);                                        \
        float sr = wshr1(r);                                                    \
        sr = lane0 ? r0 : sr;                                                   \
        r = fmaf(sr, pev, r * pbv);                                             \
        const bool cap = (d == cap_d);                                          \
        savedV = cap ? (tlpos ? r : r0) : savedV;                               \
        savedC = cap ? (tlpos ? Rc + pcj : Rc) : savedC;                        \
        Rc += pcj;                                                              \
    }                                                                           \
    {                                                                           \
        float m = wave_max64(r);                                                \
        int mb = __float_as_int(m);                                             \
        int e = (mb >> 23) - 127;                                               \
        e = (mb >= 0x00800000) ? e : 0;                                         \
        float sc = __int_as_float((127 - e) << 23);                             \
        r *= sc;  r0 *= sc;  Rc += (float)e;                                    \
    }                                                                           \
} while (0)

#define CHUNK_BODY(c_) do {                                                     \
    const float4* pvb  = sPV[(c_) & 1];                                         \
    const float4* pcb4 = (const float4*)sPC[(c_) & 1];                          \
    const int d0 = CH_ * (c_);                                                  \
    float4 pvA[4], pvB[4];                                                      \
    float4 pcA[2], pcB[2];                                                      \
    LOADG(pvA, pcA, 0);                                                         \
    for (int g = 0; g < 8; g += 2) {                                            \
        LOADG(pvB, pcB, g + 1);                                                 \
        COMPG(pvA, pcA, g);                                                     \
        if (g + 2 < 8) LOADG(pvA, pcA, g + 2);                                  \
        COMPG(pvB, pcB, g + 1);                                                 \
    }                                                                           \
} while (0)

__global__ __launch_bounds__(512) void k_alpha(
    const float* __restrict__ BLD, const float* __restrict__ EMD,
    const int* __restrict__ il_, const int* __restrict__ tl_,
    float* __restrict__ sink)
{
    __shared__ __align__(16) float  sRBL[2][17 * 256];   // raw BL (34 KB)
    __shared__ __align__(16) float  sREM[2][16 * 256];   // raw EM (32 KB)
    __shared__ __align__(16) float4 sPV[2][32 * 64];     // packed pairs (64 KB)
    __shared__ __align__(16) float  sPC[2][CH_];         // refs (512 B)

    const int b    = blockIdx.x;
    const int wave = threadIdx.x >> 6;
    const int lane = threadIdx.x & 63;
    const int il   = il_[b];
    const int tl   = tl_[b];
    const int dstar = il - 1 + tl;
    const float* BLb = BLD + (size_t)b * NDIAGP_ * U1_;
    const float* EMb = EMD + (size_t)b * NDIAGP_ * U_;
    const float fblank = BLb[(size_t)dstar * U1_ + tl];

    const bool lane0 = (lane == 0);
    const bool tlpos = (tl > 0);
    const int  cap_d = tlpos ? dstar : il;

    float r  = 0.0f;
    float r0 = 1.0f;
    float Rc = 0.0f;
    float savedV = 1.0f, savedC = 0.0f;

    GLDS(0);
    __syncthreads();
    GLDS(1);
    CONV(0);
    __syncthreads();

    for (int c = 0; c < 5; ++c) {
        if (c + 2 <= 4) GLDS(c + 2);
        if (c + 1 <= 4) CONV(c + 1);
        if (wave == 0) { CHUNK_BODY(c); }
        __syncthreads();
    }

    if (wave == 0) {
        const int sl = tlpos ? (tl - 1) : 0;
        float sv = __int_as_float(
            __builtin_amdgcn_readlane(__float_as_int(savedV), sl));
        float sc = __int_as_float(
            __builtin_amdgcn_readlane(__float_as_int(savedC), 0));
        if (lane == 0)
            atomicAdd(sink, -(sc + log2f(sv) + fblank) * (LN2_ / B_));
    }
}

extern "C" void kernel_launch(void* const* d_in, const int* in_sizes, int n_in,
                              void* d_out, int out_size, void* d_ws, size_t ws_size,
                              hipStream_t stream)
{
    const float* enc     = (const float*)d_in[0];
    const float* dec     = (const float*)d_in[1];
    const int*   targets = (const int*)d_in[2];
    const int*   il      = (const int*)d_in[3];
    const int*   tl      = (const int*)d_in[4];
    float*       out     = (float*)d_out;

    float* BLD = (float*)d_ws;                            // B*NDIAGP*U1
    float* EMD = BLD + (size_t)B_ * NDIAGP_ * U1_;        // B*NDIAGP*U_

    k_logprobs<<<B_ * T_ / NT_, 256, 0, stream>>>(enc, dec, targets, BLD, EMD, out);
    k_alpha<<<B_, 512, 0, stream>>>(BLD, EMD, il, tl, out);
}